// Round 10
// baseline (271.140 us; speedup 1.0000x reference)
//
#include <hip/hip_runtime.h>
#include <stdint.h>

typedef unsigned short u16;
typedef __bf16 bf16x8 __attribute__((ext_vector_type(8)));
typedef float  f32x4  __attribute__((ext_vector_type(4)));

#define B_  2
#define T_  1024
#define C_  2048
#define H_  16
#define D_  128
#define NTENS 4194304   // elements in x and in each W (2*1024*2048 == 2048*2048)

__device__ __forceinline__ u16 f2bf(float f) {
    union { float f; uint32_t u; } v; v.f = f;
    uint32_t r = (v.u + 0x7FFFu + ((v.u >> 16) & 1u)) >> 16;
    return (u16)r;
}
__device__ __forceinline__ float bf2f(u16 h) {
    union { uint32_t u; float f; } v; v.u = ((uint32_t)h) << 16;
    return v.f;
}
// 2^x via v_exp_f32 (hardware exp IS base-2). __exp2f collides with a glibc
// math.h macro on this toolchain; the amdgcn builtin has no such collision.
__device__ __forceinline__ float fexp2(float x) {
    return __builtin_amdgcn_exp2f(x);
}

// ---------------------------------------------------------------------------
// fp32 -> bf16 conversion; z in [0,5): {x,Wq,Wk,Wv,Wo}. z==5: RoPE table
// (first 256 blocks). z==6: zero-init the fp32 output (split-K gemm_out
// accumulates with atomicAdd) — folded here to save a launch.
// ---------------------------------------------------------------------------
__global__ __launch_bounds__(256) void k_convert(
    const float* __restrict__ x, const float* __restrict__ wq,
    const float* __restrict__ wk, const float* __restrict__ wv,
    const float* __restrict__ wo, u16* __restrict__ dst,
    float* __restrict__ ct, float* __restrict__ st, float* __restrict__ outz)
{
    int z = blockIdx.z;
    if (z == 5) {
        int idx = blockIdx.x * 256 + threadIdx.x;
        if (idx < 65536) {
            int t = idx >> 6, d = idx & 63;
            float inv = expf(-(float)d * (9.210340371976184f / 64.0f));
            float th = (float)t * inv;
            float s, c;
            sincosf(th, &s, &c);
            ct[idx] = c;
            st[idx] = s;
        }
        return;
    }
    if (z == 6) {
        size_t i = ((size_t)blockIdx.x * 256 + threadIdx.x) * 4;
        *(float4*)(outz + i) = make_float4(0.f, 0.f, 0.f, 0.f);
        return;
    }
    const float* src = (z == 0) ? x : (z == 1) ? wq : (z == 2) ? wk : (z == 3) ? wv : wo;
    u16* d = dst + (size_t)z * NTENS;
    size_t i = ((size_t)blockIdx.x * 256 + threadIdx.x) * 4;
    float4 v = *(const float4*)(src + i);
    ushort4 o;
    o.x = f2bf(v.x); o.y = f2bf(v.y); o.z = f2bf(v.z); o.w = f2bf(v.w);
    *(ushort4*)(d + i) = o;
}

// ---------------------------------------------------------------------------
// NT-form MTILE x 128 MFMA tile GEMM with async global->LDS staging.
// XOR-swizzled LDS (zero bank conflicts). Waves 1x4; wave w owns cols
// {16w..16w+15} and {64+16w..+15} so the RoPE pair (d,d+64) is in-lane.
// MTILE=64 @ 6 blk/CU is the verified optimum for THIS problem size and
// 2-barrier structure (rounds 1 & 3: both 128-row variants -> 92-96us).
// EPI: 0 = fp32 store, 1 = bf16 store, 2 = QKV epilogue, 3 = fp32 atomicAdd
//      (split-K partial accumulation; out pre-zeroed by k_convert z==6):
//   z<2  -> RoPE in registers, bf16 store [t][c].  Q's scale folds in
//           log2(e) so flash softmax can use exp2 (v_exp_f32 IS 2^x):
//           0.08838834764831845 * 1.4426950408889634 = 0.12751743368.
//   z==2 -> V with FUSED TRANSPOSE: store bf16 to vt [bh][d][t] directly.
// ---------------------------------------------------------------------------
template<int MTILE, int EPI>
__device__ __forceinline__ void gemm_tile_nt(
    const u16* __restrict__ A, int lda,
    const u16* __restrict__ Bp, int ldb,
    void* __restrict__ Cp, int ldc,
    int m0, int n0, int K,
    u16* SMEM, const float* __restrict__ ct, const float* __restrict__ st, int z)
{
    constexpr int MF  = MTILE / 16;
    constexpr int ACH = MTILE / 32;
    u16* As = SMEM;
    u16* Bs = SMEM + MTILE * 64;

    const int tid  = threadIdx.x;
    const int wave = tid >> 6;
    const int lane = tid & 63;
    const int frow = lane & 15;
    const int quad = lane >> 4;

    const int lrow8  = lane >> 3;
    const int slot   = lane & 7;
    const int gchunk = slot ^ lrow8;

    f32x4 acc[MF][2] = {};

    size_t aoff[ACH], boff[4];
#pragma unroll
    for (int i = 0; i < ACH; ++i) {
        int c = (i << 2) + wave;
        int r = (c << 3) + lrow8;
        aoff[i] = (size_t)(m0 + r) * lda + (gchunk << 3);
    }
#pragma unroll
    for (int i = 0; i < 4; ++i) {
        int r = (i << 5) + (wave << 3) + lrow8;
        boff[i] = (size_t)(n0 + r) * ldb + (gchunk << 3);
    }

    for (int kt = 0; kt < K; kt += 64) {
#pragma unroll
        for (int i = 0; i < ACH; ++i) {
            int c = (i << 2) + wave;
            __builtin_amdgcn_global_load_lds(
                (const __attribute__((address_space(1))) void*)(A + aoff[i] + kt),
                (__attribute__((address_space(3))) void*)(As + (c << 9)), 16, 0, 0);
        }
#pragma unroll
        for (int i = 0; i < 4; ++i) {
            int c = (i << 2) + wave;
            __builtin_amdgcn_global_load_lds(
                (const __attribute__((address_space(1))) void*)(Bp + boff[i] + kt),
                (__attribute__((address_space(3))) void*)(Bs + (c << 9)), 16, 0, 0);
        }
        __syncthreads();

#pragma unroll
        for (int ks = 0; ks < 2; ++ks) {
            int lk = (ks << 2) + quad;
            bf16x8 af[MF], bfv[2];
#pragma unroll
            for (int i = 0; i < MF; ++i) {
                int ar = (i << 4) + frow;
                af[i] = *(const bf16x8*)&As[ar * 64 + ((lk ^ (frow & 7)) << 3)];
            }
#pragma unroll
            for (int j = 0; j < 2; ++j) {
                int br = (wave << 4) + (j << 6) + frow;
                bfv[j] = *(const bf16x8*)&Bs[br * 64 + ((lk ^ (frow & 7)) << 3)];
            }
#pragma unroll
            for (int i = 0; i < MF; ++i)
#pragma unroll
                for (int j = 0; j < 2; ++j)
                    acc[i][j] = __builtin_amdgcn_mfma_f32_16x16x32_bf16(
                        af[i], bfv[j], acc[i][j], 0, 0, 0);
        }
        __syncthreads();
    }

    if constexpr (EPI == 2) {
        if (z < 2) {
            const int d = (wave << 4) + frow;
            // z==0 (Q): 1/sqrt(128) * log2(e)  — see header comment.
            const float sc = (z == 0) ? 0.12751743368f : 1.0f;
            u16* Op = (u16*)Cp;
#pragma unroll
            for (int i = 0; i < MF; ++i)
#pragma unroll
                for (int r = 0; r < 4; ++r) {
                    int m = m0 + (i << 4) + (quad << 2) + r;
                    int t = m & 1023;
                    float c = ct[t * 64 + d], s = st[t * 64 + d];
                    float a = acc[i][0][r], bb = acc[i][1][r];
                    Op[(size_t)m * ldc + n0 + d]      = f2bf((a * c - bb * s) * sc);
                    Op[(size_t)m * ldc + n0 + d + 64] = f2bf((bb * c + a * s) * sc);
                }
            return;
        }
        // z == 2: V with fused transpose. Cp is vt [bh][d][t]; this tile's
        // n-range [n0, n0+128) is exactly head h = n0>>7.
        const int hh = n0 >> 7;
        const int bI = m0 >> 10;
        const int t0 = m0 & 1023;
        u16* Vp = (u16*)Cp + ((size_t)((bI << 4) + hh)) * (D_ * T_);
#pragma unroll
        for (int i = 0; i < MF; ++i)
#pragma unroll
            for (int j = 0; j < 2; ++j) {
                int d = (wave << 4) + (j << 6) + frow;
                int t = t0 + (i << 4) + (quad << 2);
                ushort4 o;
                o.x = f2bf(acc[i][j][0]); o.y = f2bf(acc[i][j][1]);
                o.z = f2bf(acc[i][j][2]); o.w = f2bf(acc[i][j][3]);
                *(ushort4*)&Vp[(size_t)d * T_ + t] = o;
            }
        return;
    }

#pragma unroll
    for (int i = 0; i < MF; ++i)
#pragma unroll
        for (int j = 0; j < 2; ++j)
#pragma unroll
            for (int r = 0; r < 4; ++r) {
                int m = m0 + (i << 4) + (quad << 2) + r;
                int n = n0 + (wave << 4) + (j << 6) + frow;
                if constexpr (EPI == 0)
                    ((float*)Cp)[(size_t)m * ldc + n] = acc[i][j][r];
                else if constexpr (EPI == 3)
                    atomicAdd(&((float*)Cp)[(size_t)m * ldc + n], acc[i][j][r]);
                else
                    ((u16*)Cp)[(size_t)m * ldc + n] = f2bf(acc[i][j][r]);
            }
}

// ---------------------------------------------------------------------------
// QKV projection with in-register RoPE epilogue (Q/K) and fused V transpose
// to [bh][d][t]. 64x128 tiles, grid (16,32,3) = 1536 blocks = 6 blk/CU.
// ---------------------------------------------------------------------------
__global__ __launch_bounds__(256) void k_gemm_qkv(
    const u16* __restrict__ xb, const u16* __restrict__ wq,
    const u16* __restrict__ wk, const u16* __restrict__ wv,
    u16* __restrict__ q, u16* __restrict__ k, u16* __restrict__ vt,
    const float* __restrict__ ct, const float* __restrict__ st)
{
    __shared__ u16 SMEM[64 * 64 + 128 * 64];
    int z = blockIdx.z;
    const u16* Bp = (z == 0) ? wq : (z == 1) ? wk : wv;
    u16* Op       = (z == 0) ? q  : (z == 1) ? k  : vt;
    gemm_tile_nt<64, 2>(xb, C_, Bp, C_, Op, C_,
                        blockIdx.y * 64, blockIdx.x * 128, C_, SMEM, ct, st, z);
}

// ---------------------------------------------------------------------------
// Fused flash attention v3 (R6, verified best): KV-tile 128, Q in registers,
// K and V^T staged with global_load_lds. Split-wait staging: B1 waits only K
// (vmcnt(8)); V latency hides under QK^T+softmax, drained by B2's
// __syncthreads. P overwrites Ks (stride 136). Softmax in exp2 domain
// (Q pre-scaled by log2(e)). 4 waves x 16 q-rows, 2 blk/CU — verified
// occupancy sweet spot (R9: 2-wave/32-row variant -25us; R7: deep pipeline
// -4us; R8: defer-max -11us; R4: setprio -7us. Flash closed for edits).
// ---------------------------------------------------------------------------
__global__ __launch_bounds__(256) void k_flash(
    const u16* __restrict__ qb, const u16* __restrict__ kb,
    const u16* __restrict__ vt, u16* __restrict__ yb)
{
    __shared__ u16 Ks[128 * 128];   // [tok][d]; P (stride 136) reuses this
    __shared__ u16 Vs[128 * 128];   // [d][tok]

    const int bx  = blockIdx.x;
    const int bh  = bx & 31, b = bh >> 4, h = bh & 15;
    const int qt  = (bx < 256) ? (15 - (bx >> 5)) : ((bx >> 5) - 8);
    const int KT  = (qt >> 1) + 1;
    const int tid = threadIdx.x, wave = tid >> 6, lane = tid & 63;
    const int frow = lane & 15, quad = lane >> 4;

    const u16* qbase = qb + (size_t)b * (T_ * C_) + h * D_;
    const u16* kbase = kb + (size_t)b * (T_ * C_) + h * D_;
    const u16* vbase = vt + (size_t)bh * (D_ * T_);
    const int q0 = qt << 6;

    // ---- Q fragments in registers (wave w owns q-rows q0+16w..+15) ----
    bf16x8 qf[4];
#pragma unroll
    for (int ks = 0; ks < 4; ++ks)
        qf[ks] = *(const bf16x8*)&qbase[(size_t)(q0 + (wave << 4) + frow) * C_
                                        + (ks << 5) + (quad << 3)];

    f32x4 Y[8] = {};
    float mrow[4], lrow[4];
#pragma unroll
    for (int r = 0; r < 4; ++r) { mrow[r] = -3e38f; lrow[r] = 0.f; }

    const int tok = q0 + (wave << 4) + (quad << 2);  // + r = global q row

    for (int kt = 0; kt < KT; ++kt) {
        const int k0 = kt << 7;
        // ---- stage K tile (8 loads), then V^T tile (8 loads) ----
        {
            const int r4 = lane >> 4, s16 = lane & 15;
#pragma unroll
            for (int i = 0; i < 8; ++i) {
                int c = (i << 2) + wave;             // 0..31, 4 rows each
                int row = (c << 2) + r4;             // 0..127
                int g = (s16 & 8) | ((s16 & 7) ^ (row & 7));
                __builtin_amdgcn_global_load_lds(
                    (const __attribute__((address_space(1))) void*)(kbase + (size_t)(k0 + row) * C_ + (g << 3)),
                    (__attribute__((address_space(3))) void*)(Ks + (c << 9)), 16, 0, 0);
            }
#pragma unroll
            for (int i = 0; i < 8; ++i) {
                int c = (i << 2) + wave;
                int row = (c << 2) + r4;
                int g = (s16 & 8) | ((s16 & 7) ^ (row & 7));
                __builtin_amdgcn_global_load_lds(
                    (const __attribute__((address_space(1))) void*)(vbase + (size_t)row * T_ + k0 + (g << 3)),
                    (__attribute__((address_space(3))) void*)(Vs + (c << 9)), 16, 0, 0);
            }
        }
        // B1: wait own K loads only (8 V loads remain in flight), then
        // barrier -> all waves' K staged. sched_barrier fences ds_read
        // hoisting across the partial wait (rule #18).
        asm volatile("s_waitcnt vmcnt(8)" ::: "memory");
        __builtin_amdgcn_sched_barrier(0);
        __builtin_amdgcn_s_barrier();
        __builtin_amdgcn_sched_barrier(0);

        // ---- S = q K^T  (wave-tile 16 x 128) ----
        f32x4 S[8] = {};
#pragma unroll
        for (int ks = 0; ks < 4; ++ks) {
            int lk = (ks << 2) + quad;
            int sw = ((lk & 8) | ((lk & 7) ^ (frow & 7))) << 3;
#pragma unroll
            for (int jj = 0; jj < 8; ++jj) {
                bf16x8 bb = *(const bf16x8*)&Ks[((jj << 4) + frow) * 128 + sw];
                S[jj] = __builtin_amdgcn_mfma_f32_16x16x32_bf16(qf[ks], bb, S[jj], 0, 0, 0);
            }
        }

        // ---- causal mask (only the last kv-tile intersects the diagonal) ----
        if (kt == KT - 1) {
#pragma unroll
            for (int jj = 0; jj < 8; ++jj) {
                int colg = k0 + (jj << 4) + frow;
#pragma unroll
                for (int r = 0; r < 4; ++r)
                    if (colg > tok + r) S[jj][r] = -1e30f;
            }
        }

        // ---- online softmax in exp2 domain (rows in 16-lane frow groups) ----
        float al[4];
#pragma unroll
        for (int r = 0; r < 4; ++r) {
            float tm = -3e38f;
#pragma unroll
            for (int jj = 0; jj < 8; ++jj) tm = fmaxf(tm, S[jj][r]);
#pragma unroll
            for (int off = 8; off > 0; off >>= 1) tm = fmaxf(tm, __shfl_xor(tm, off));
            float mn = fmaxf(mrow[r], tm);
            al[r] = fexp2(mrow[r] - mn);
            mrow[r] = mn;
            float rs = 0.f;
#pragma unroll
            for (int jj = 0; jj < 8; ++jj) {
                float e = fexp2(S[jj][r] - mn);
                S[jj][r] = e;
                rs += e;
            }
#pragma unroll
            for (int off = 8; off > 0; off >>= 1) rs += __shfl_xor(rs, off);
            lrow[r] = lrow[r] * al[r] + rs;
        }
#pragma unroll
        for (int dj = 0; dj < 8; ++dj)
#pragma unroll
            for (int r = 0; r < 4; ++r) Y[dj][r] *= al[r];

        __syncthreads();   // B2: Ks reads done by all waves (safe to overwrite
                           // with P) AND vmcnt(0) drain -> Vs fully staged.

        // ---- write P into Ks region (A-layout, stride 136) ----
        u16* Ps = Ks;
#pragma unroll
        for (int jj = 0; jj < 8; ++jj)
#pragma unroll
            for (int r = 0; r < 4; ++r)
                Ps[((wave << 4) + (quad << 2) + r) * 136 + (jj << 4) + frow] = f2bf(S[jj][r]);

        // ---- Y += P V ----
#pragma unroll
        for (int ks = 0; ks < 4; ++ks) {
            bf16x8 pa = *(const bf16x8*)&Ps[((wave << 4) + frow) * 136 + (ks << 5) + (quad << 3)];
            int lk = (ks << 2) + quad;
            int sw = ((lk & 8) | ((lk & 7) ^ (frow & 7))) << 3;
#pragma unroll
            for (int dj = 0; dj < 8; ++dj) {
                bf16x8 vv = *(const bf16x8*)&Vs[((dj << 4) + frow) * 128 + sw];
                Y[dj] = __builtin_amdgcn_mfma_f32_16x16x32_bf16(pa, vv, Y[dj], 0, 0, 0);
            }
        }
        __syncthreads();   // B3: PV reads done before next-iter staging
    }

    // ---- epilogue: Y /= l, store to yb [b,t,h,d] ----
    u16* ybase = yb + (size_t)b * (T_ * C_) + h * D_;
#pragma unroll
    for (int r = 0; r < 4; ++r) {
        float inv = 1.0f / lrow[r];
#pragma unroll
        for (int dj = 0; dj < 8; ++dj)
            ybase[(size_t)(tok + r) * C_ + (dj << 4) + frow] = f2bf(Y[dj][r] * inv);
    }
}

// ---------------------------------------------------------------------------
// out = y @ Wo^T, fp32 output via SPLIT-K=3 + atomicAdd (out pre-zeroed by
// k_convert z==6). Grid (16,32,3) = 1536 blocks = 6 blk/CU — the verified
// occupancy regime for this tile (2 blk/CU at unsplit K was the same
// under-occupancy failure mode rounds 1/3 measured). K-chunks 704/704/640
// (multiples of BK=64); fp32 add reorder is far below the 1.5e-2 tolerance.
// ---------------------------------------------------------------------------
__global__ __launch_bounds__(256) void k_gemm_out(
    const u16* __restrict__ yb, const u16* __restrict__ wo, float* __restrict__ out)
{
    __shared__ u16 SMEM[64 * 64 + 128 * 64];
    int z = blockIdx.z;
    int ks0  = z * 704;                    // 0, 704, 1408
    int klen = (z == 2) ? 640 : 704;
    gemm_tile_nt<64, 3>(yb + ks0, C_, wo + ks0, C_, out, C_,
                        blockIdx.y * 64, blockIdx.x * 128, klen,
                        SMEM, nullptr, nullptr, 0);
}

// ---------------------------------------------------------------------------
extern "C" void kernel_launch(void* const* d_in, const int* in_sizes, int n_in,
                              void* d_out, int out_size, void* d_ws, size_t ws_size,
                              hipStream_t stream)
{
    (void)in_sizes; (void)n_in; (void)out_size; (void)ws_size;
    const float* x  = (const float*)d_in[0];
    const float* Wq = (const float*)d_in[1];
    const float* Wk = (const float*)d_in[2];
    const float* Wv = (const float*)d_in[3];
    const float* Wo = (const float*)d_in[4];

    u16* ws  = (u16*)d_ws;
    u16* xb  = ws;
    u16* wqb = ws + (size_t)1 * NTENS;
    u16* wkb = ws + (size_t)2 * NTENS;
    u16* wvb = ws + (size_t)3 * NTENS;
    u16* wob = ws + (size_t)4 * NTENS;
    u16* qb  = ws + (size_t)5 * NTENS;
    u16* kb  = ws + (size_t)6 * NTENS;
    // slot 7 (vb) unused since V is written pre-transposed by the QKV GEMM
    u16* yb  = ws + (size_t)8 * NTENS;
    u16* vt  = ws + (size_t)9 * NTENS;         // [bh][d][t]
    float* ct = (float*)(ws + (size_t)10 * NTENS);
    float* st = ct + 65536;

    k_convert <<<dim3(4096, 1, 7), 256, 0, stream>>>(x, Wq, Wk, Wv, Wo, ws, ct, st,
                                                     (float*)d_out);
    k_gemm_qkv<<<dim3(16, 32, 3), 256, 0, stream>>>(xb, wqb, wkb, wvb, qb, kb, vt, ct, st);
    k_flash   <<<dim3(512), 256, 0, stream>>>(qb, kb, vt, yb);
    k_gemm_out<<<dim3(16, 32, 3), 256, 0, stream>>>(yb, wob, (float*)d_out);
}

// Round 11
// 240.252 us; speedup vs baseline: 1.1286x; 1.1286x over previous
//
#include <hip/hip_runtime.h>
#include <stdint.h>

typedef unsigned short u16;
typedef __bf16 bf16x8 __attribute__((ext_vector_type(8)));
typedef float  f32x4  __attribute__((ext_vector_type(4)));

#define B_  2
#define T_  1024
#define C_  2048
#define H_  16
#define D_  128
#define NTENS 4194304   // elements in x and in each W (2*1024*2048 == 2048*2048)

__device__ __forceinline__ u16 f2bf(float f) {
    union { float f; uint32_t u; } v; v.f = f;
    uint32_t r = (v.u + 0x7FFFu + ((v.u >> 16) & 1u)) >> 16;
    return (u16)r;
}
__device__ __forceinline__ float bf2f(u16 h) {
    union { uint32_t u; float f; } v; v.u = ((uint32_t)h) << 16;
    return v.f;
}
// 2^x via v_exp_f32 (hardware exp IS base-2). __exp2f collides with a glibc
// math.h macro on this toolchain; the amdgcn builtin has no such collision.
__device__ __forceinline__ float fexp2(float x) {
    return __builtin_amdgcn_exp2f(x);
}

// ---------------------------------------------------------------------------
// fp32 -> bf16 conversion; z in [0,5): {x,Wq,Wk,Wv,Wo}. z==5: RoPE table
// (first 64 blocks only) — folded here to save a launch.
// ---------------------------------------------------------------------------
__global__ __launch_bounds__(256) void k_convert(
    const float* __restrict__ x, const float* __restrict__ wq,
    const float* __restrict__ wk, const float* __restrict__ wv,
    const float* __restrict__ wo, u16* __restrict__ dst,
    float* __restrict__ ct, float* __restrict__ st)
{
    int z = blockIdx.z;
    if (z == 5) {
        int idx = blockIdx.x * 256 + threadIdx.x;
        if (idx < 65536) {
            int t = idx >> 6, d = idx & 63;
            float inv = expf(-(float)d * (9.210340371976184f / 64.0f));
            float th = (float)t * inv;
            float s, c;
            sincosf(th, &s, &c);
            ct[idx] = c;
            st[idx] = s;
        }
        return;
    }
    const float* src = (z == 0) ? x : (z == 1) ? wq : (z == 2) ? wk : (z == 3) ? wv : wo;
    u16* d = dst + (size_t)z * NTENS;
    size_t i = ((size_t)blockIdx.x * 256 + threadIdx.x) * 4;
    float4 v = *(const float4*)(src + i);
    ushort4 o;
    o.x = f2bf(v.x); o.y = f2bf(v.y); o.z = f2bf(v.z); o.w = f2bf(v.w);
    *(ushort4*)(d + i) = o;
}

// ---------------------------------------------------------------------------
// NT-form MTILE x 128 MFMA tile GEMM with async global->LDS staging.
// XOR-swizzled LDS (zero bank conflicts). Waves 1x4; wave w owns cols
// {16w..16w+15} and {64+16w..+15} so the RoPE pair (d,d+64) is in-lane.
// MTILE=64 @ 6 blk/CU is the verified optimum for THIS problem size and
// 2-barrier structure (R1/R3: both 128-row variants -> 92-96us, occupancy
// halves; R10: split-K atomics -> +32us from tripled output traffic).
// EPI: 0 = fp32 store, 1 = bf16 store, 2 = QKV epilogue:
//   z<2  -> RoPE in registers, bf16 store [t][c].  Q's scale folds in
//           log2(e) so flash softmax can use exp2 (v_exp_f32 IS 2^x):
//           0.08838834764831845 * 1.4426950408889634 = 0.12751743368.
//   z==2 -> V with FUSED TRANSPOSE: store bf16 to vt [bh][d][t] directly
//           (tile n-range == one head since D==128; acc[i][j][0..3] are 4
//            consecutive tokens at fixed d -> contiguous ushort4 in [d][t])
// ---------------------------------------------------------------------------
template<int MTILE, int EPI>
__device__ __forceinline__ void gemm_tile_nt(
    const u16* __restrict__ A, int lda,
    const u16* __restrict__ Bp, int ldb,
    void* __restrict__ Cp, int ldc,
    int m0, int n0, int K,
    u16* SMEM, const float* __restrict__ ct, const float* __restrict__ st, int z)
{
    constexpr int MF  = MTILE / 16;
    constexpr int ACH = MTILE / 32;
    u16* As = SMEM;
    u16* Bs = SMEM + MTILE * 64;

    const int tid  = threadIdx.x;
    const int wave = tid >> 6;
    const int lane = tid & 63;
    const int frow = lane & 15;
    const int quad = lane >> 4;

    const int lrow8  = lane >> 3;
    const int slot   = lane & 7;
    const int gchunk = slot ^ lrow8;

    f32x4 acc[MF][2] = {};

    size_t aoff[ACH], boff[4];
#pragma unroll
    for (int i = 0; i < ACH; ++i) {
        int c = (i << 2) + wave;
        int r = (c << 3) + lrow8;
        aoff[i] = (size_t)(m0 + r) * lda + (gchunk << 3);
    }
#pragma unroll
    for (int i = 0; i < 4; ++i) {
        int r = (i << 5) + (wave << 3) + lrow8;
        boff[i] = (size_t)(n0 + r) * ldb + (gchunk << 3);
    }

    for (int kt = 0; kt < K; kt += 64) {
#pragma unroll
        for (int i = 0; i < ACH; ++i) {
            int c = (i << 2) + wave;
            __builtin_amdgcn_global_load_lds(
                (const __attribute__((address_space(1))) void*)(A + aoff[i] + kt),
                (__attribute__((address_space(3))) void*)(As + (c << 9)), 16, 0, 0);
        }
#pragma unroll
        for (int i = 0; i < 4; ++i) {
            int c = (i << 2) + wave;
            __builtin_amdgcn_global_load_lds(
                (const __attribute__((address_space(1))) void*)(Bp + boff[i] + kt),
                (__attribute__((address_space(3))) void*)(Bs + (c << 9)), 16, 0, 0);
        }
        __syncthreads();

#pragma unroll
        for (int ks = 0; ks < 2; ++ks) {
            int lk = (ks << 2) + quad;
            bf16x8 af[MF], bfv[2];
#pragma unroll
            for (int i = 0; i < MF; ++i) {
                int ar = (i << 4) + frow;
                af[i] = *(const bf16x8*)&As[ar * 64 + ((lk ^ (frow & 7)) << 3)];
            }
#pragma unroll
            for (int j = 0; j < 2; ++j) {
                int br = (wave << 4) + (j << 6) + frow;
                bfv[j] = *(const bf16x8*)&Bs[br * 64 + ((lk ^ (frow & 7)) << 3)];
            }
#pragma unroll
            for (int i = 0; i < MF; ++i)
#pragma unroll
                for (int j = 0; j < 2; ++j)
                    acc[i][j] = __builtin_amdgcn_mfma_f32_16x16x32_bf16(
                        af[i], bfv[j], acc[i][j], 0, 0, 0);
        }
        __syncthreads();
    }

    if constexpr (EPI == 2) {
        if (z < 2) {
            const int d = (wave << 4) + frow;
            // z==0 (Q): 1/sqrt(128) * log2(e)  — see header comment.
            const float sc = (z == 0) ? 0.12751743368f : 1.0f;
            u16* Op = (u16*)Cp;
#pragma unroll
            for (int i = 0; i < MF; ++i)
#pragma unroll
                for (int r = 0; r < 4; ++r) {
                    int m = m0 + (i << 4) + (quad << 2) + r;
                    int t = m & 1023;
                    float c = ct[t * 64 + d], s = st[t * 64 + d];
                    float a = acc[i][0][r], bb = acc[i][1][r];
                    Op[(size_t)m * ldc + n0 + d]      = f2bf((a * c - bb * s) * sc);
                    Op[(size_t)m * ldc + n0 + d + 64] = f2bf((bb * c + a * s) * sc);
                }
            return;
        }
        // z == 2: V with fused transpose. Cp is vt [bh][d][t]; this tile's
        // n-range [n0, n0+128) is exactly head h = n0>>7.
        const int hh = n0 >> 7;
        const int bI = m0 >> 10;
        const int t0 = m0 & 1023;
        u16* Vp = (u16*)Cp + ((size_t)((bI << 4) + hh)) * (D_ * T_);
#pragma unroll
        for (int i = 0; i < MF; ++i)
#pragma unroll
            for (int j = 0; j < 2; ++j) {
                int d = (wave << 4) + (j << 6) + frow;
                int t = t0 + (i << 4) + (quad << 2);
                ushort4 o;
                o.x = f2bf(acc[i][j][0]); o.y = f2bf(acc[i][j][1]);
                o.z = f2bf(acc[i][j][2]); o.w = f2bf(acc[i][j][3]);
                *(ushort4*)&Vp[(size_t)d * T_ + t] = o;
            }
        return;
    }

#pragma unroll
    for (int i = 0; i < MF; ++i)
#pragma unroll
        for (int j = 0; j < 2; ++j)
#pragma unroll
            for (int r = 0; r < 4; ++r) {
                int m = m0 + (i << 4) + (quad << 2) + r;
                int n = n0 + (wave << 4) + (j << 6) + frow;
                if constexpr (EPI == 0)
                    ((float*)Cp)[(size_t)m * ldc + n] = acc[i][j][r];
                else
                    ((u16*)Cp)[(size_t)m * ldc + n] = f2bf(acc[i][j][r]);
            }
}

// ---------------------------------------------------------------------------
// QKV projection with in-register RoPE epilogue (Q/K) and fused V transpose
// to [bh][d][t]. 64x128 tiles, grid (16,32,3) = 1536 blocks = 6 blk/CU.
// ---------------------------------------------------------------------------
__global__ __launch_bounds__(256) void k_gemm_qkv(
    const u16* __restrict__ xb, const u16* __restrict__ wq,
    const u16* __restrict__ wk, const u16* __restrict__ wv,
    u16* __restrict__ q, u16* __restrict__ k, u16* __restrict__ vt,
    const float* __restrict__ ct, const float* __restrict__ st)
{
    __shared__ u16 SMEM[64 * 64 + 128 * 64];
    int z = blockIdx.z;
    const u16* Bp = (z == 0) ? wq : (z == 1) ? wk : wv;
    u16* Op       = (z == 0) ? q  : (z == 1) ? k  : vt;
    gemm_tile_nt<64, 2>(xb, C_, Bp, C_, Op, C_,
                        blockIdx.y * 64, blockIdx.x * 128, C_, SMEM, ct, st, z);
}

// ---------------------------------------------------------------------------
// Fused flash attention v3 (R6, verified best of 10 rounds): KV-tile 128,
// Q in registers, K and V^T staged with global_load_lds (V pre-transposed
// by the QKV GEMM epilogue). Grid 512, LPT pairing (pairs sum 9).
// LDS 64 KB: Ks[128x128] (reused as P, stride 136), Vs[128x128] ([d][tok]).
// Split-wait staging: issue K loads then V loads; B1 waits only K
// (s_waitcnt vmcnt(8) + raw s_barrier) so V's memory latency hides under
// QK^T + softmax. B2's __syncthreads drains vmcnt(0) (compiler-guaranteed)
// before any wave reads Vs in PV, and before Ks is overwritten with P.
// Softmax runs in exp2 domain (Q pre-scaled by log2(e) in the projection).
// CLOSED for structural edits — all measured negative on this shape:
//   R4 setprio (-7us, lockstep waves), R7 cross-iter pipeline (-4us,
//   co-resident block already hides latency), R8 defer-max/tree-max
//   (-11us), R9 2-wave/32-row (-25us, 1 wave/SIMD starves).
// ---------------------------------------------------------------------------
__global__ __launch_bounds__(256) void k_flash(
    const u16* __restrict__ qb, const u16* __restrict__ kb,
    const u16* __restrict__ vt, u16* __restrict__ yb)
{
    __shared__ u16 Ks[128 * 128];   // [tok][d]; P (stride 136) reuses this
    __shared__ u16 Vs[128 * 128];   // [d][tok]

    const int bx  = blockIdx.x;
    const int bh  = bx & 31, b = bh >> 4, h = bh & 15;
    const int qt  = (bx < 256) ? (15 - (bx >> 5)) : ((bx >> 5) - 8);
    const int KT  = (qt >> 1) + 1;
    const int tid = threadIdx.x, wave = tid >> 6, lane = tid & 63;
    const int frow = lane & 15, quad = lane >> 4;

    const u16* qbase = qb + (size_t)b * (T_ * C_) + h * D_;
    const u16* kbase = kb + (size_t)b * (T_ * C_) + h * D_;
    const u16* vbase = vt + (size_t)bh * (D_ * T_);
    const int q0 = qt << 6;

    // ---- Q fragments in registers (wave w owns q-rows q0+16w..+15) ----
    bf16x8 qf[4];
#pragma unroll
    for (int ks = 0; ks < 4; ++ks)
        qf[ks] = *(const bf16x8*)&qbase[(size_t)(q0 + (wave << 4) + frow) * C_
                                        + (ks << 5) + (quad << 3)];

    f32x4 Y[8] = {};
    float mrow[4], lrow[4];
#pragma unroll
    for (int r = 0; r < 4; ++r) { mrow[r] = -3e38f; lrow[r] = 0.f; }

    const int tok = q0 + (wave << 4) + (quad << 2);  // + r = global q row

    for (int kt = 0; kt < KT; ++kt) {
        const int k0 = kt << 7;
        // ---- stage K tile (8 loads), then V^T tile (8 loads) ----
        {
            const int r4 = lane >> 4, s16 = lane & 15;
#pragma unroll
            for (int i = 0; i < 8; ++i) {
                int c = (i << 2) + wave;             // 0..31, 4 rows each
                int row = (c << 2) + r4;             // 0..127
                int g = (s16 & 8) | ((s16 & 7) ^ (row & 7));
                __builtin_amdgcn_global_load_lds(
                    (const __attribute__((address_space(1))) void*)(kbase + (size_t)(k0 + row) * C_ + (g << 3)),
                    (__attribute__((address_space(3))) void*)(Ks + (c << 9)), 16, 0, 0);
            }
#pragma unroll
            for (int i = 0; i < 8; ++i) {
                int c = (i << 2) + wave;
                int row = (c << 2) + r4;
                int g = (s16 & 8) | ((s16 & 7) ^ (row & 7));
                __builtin_amdgcn_global_load_lds(
                    (const __attribute__((address_space(1))) void*)(vbase + (size_t)row * T_ + k0 + (g << 3)),
                    (__attribute__((address_space(3))) void*)(Vs + (c << 9)), 16, 0, 0);
            }
        }
        // B1: wait own K loads only (8 V loads remain in flight), then
        // barrier -> all waves' K staged. sched_barrier fences ds_read
        // hoisting across the partial wait (rule #18).
        asm volatile("s_waitcnt vmcnt(8)" ::: "memory");
        __builtin_amdgcn_sched_barrier(0);
        __builtin_amdgcn_s_barrier();
        __builtin_amdgcn_sched_barrier(0);

        // ---- S = q K^T  (wave-tile 16 x 128) ----
        f32x4 S[8] = {};
#pragma unroll
        for (int ks = 0; ks < 4; ++ks) {
            int lk = (ks << 2) + quad;
            int sw = ((lk & 8) | ((lk & 7) ^ (frow & 7))) << 3;
#pragma unroll
            for (int jj = 0; jj < 8; ++jj) {
                bf16x8 bb = *(const bf16x8*)&Ks[((jj << 4) + frow) * 128 + sw];
                S[jj] = __builtin_amdgcn_mfma_f32_16x16x32_bf16(qf[ks], bb, S[jj], 0, 0, 0);
            }
        }

        // ---- causal mask (only the last kv-tile intersects the diagonal) ----
        if (kt == KT - 1) {
#pragma unroll
            for (int jj = 0; jj < 8; ++jj) {
                int colg = k0 + (jj << 4) + frow;
#pragma unroll
                for (int r = 0; r < 4; ++r)
                    if (colg > tok + r) S[jj][r] = -1e30f;
            }
        }

        // ---- online softmax in exp2 domain (rows in 16-lane frow groups) ----
        float al[4];
#pragma unroll
        for (int r = 0; r < 4; ++r) {
            float tm = -3e38f;
#pragma unroll
            for (int jj = 0; jj < 8; ++jj) tm = fmaxf(tm, S[jj][r]);
#pragma unroll
            for (int off = 8; off > 0; off >>= 1) tm = fmaxf(tm, __shfl_xor(tm, off));
            float mn = fmaxf(mrow[r], tm);
            al[r] = fexp2(mrow[r] - mn);
            mrow[r] = mn;
            float rs = 0.f;
#pragma unroll
            for (int jj = 0; jj < 8; ++jj) {
                float e = fexp2(S[jj][r] - mn);
                S[jj][r] = e;
                rs += e;
            }
#pragma unroll
            for (int off = 8; off > 0; off >>= 1) rs += __shfl_xor(rs, off);
            lrow[r] = lrow[r] * al[r] + rs;
        }
#pragma unroll
        for (int dj = 0; dj < 8; ++dj)
#pragma unroll
            for (int r = 0; r < 4; ++r) Y[dj][r] *= al[r];

        __syncthreads();   // B2: Ks reads done by all waves (safe to overwrite
                           // with P) AND vmcnt(0) drain -> Vs fully staged.

        // ---- write P into Ks region (A-layout, stride 136) ----
        u16* Ps = Ks;
#pragma unroll
        for (int jj = 0; jj < 8; ++jj)
#pragma unroll
            for (int r = 0; r < 4; ++r)
                Ps[((wave << 4) + (quad << 2) + r) * 136 + (jj << 4) + frow] = f2bf(S[jj][r]);

        // ---- Y += P V ----
#pragma unroll
        for (int ks = 0; ks < 4; ++ks) {
            bf16x8 pa = *(const bf16x8*)&Ps[((wave << 4) + frow) * 136 + (ks << 5) + (quad << 3)];
            int lk = (ks << 2) + quad;
            int sw = ((lk & 8) | ((lk & 7) ^ (frow & 7))) << 3;
#pragma unroll
            for (int dj = 0; dj < 8; ++dj) {
                bf16x8 vv = *(const bf16x8*)&Vs[((dj << 4) + frow) * 128 + sw];
                Y[dj] = __builtin_amdgcn_mfma_f32_16x16x32_bf16(pa, vv, Y[dj], 0, 0, 0);
            }
        }
        __syncthreads();   // B3: PV reads done before next-iter staging
    }

    // ---- epilogue: Y /= l, store to yb [b,t,h,d] ----
    u16* ybase = yb + (size_t)b * (T_ * C_) + h * D_;
#pragma unroll
    for (int r = 0; r < 4; ++r) {
        float inv = 1.0f / lrow[r];
#pragma unroll
        for (int dj = 0; dj < 8; ++dj)
            ybase[(size_t)(tok + r) * C_ + (dj << 4) + frow] = f2bf(Y[dj][r] * inv);
    }
}

// ---------------------------------------------------------------------------
// out = y @ Wo^T, fp32 output. 64x128 tile, grid (16,32) = 512 blocks = 2/CU.
// R10: split-K=3 + atomicAdd regressed (+32us total — tripled output traffic
// outweighs the occupancy gain). Plain store is the verified form.
// ---------------------------------------------------------------------------
__global__ __launch_bounds__(256) void k_gemm_out(
    const u16* __restrict__ yb, const u16* __restrict__ wo, float* __restrict__ out)
{
    __shared__ u16 SMEM[64 * 64 + 128 * 64];
    gemm_tile_nt<64, 0>(yb, C_, wo, C_, out, C_,
                        blockIdx.y * 64, blockIdx.x * 128, C_, SMEM, nullptr, nullptr, 0);
}

// ---------------------------------------------------------------------------
extern "C" void kernel_launch(void* const* d_in, const int* in_sizes, int n_in,
                              void* d_out, int out_size, void* d_ws, size_t ws_size,
                              hipStream_t stream)
{
    (void)in_sizes; (void)n_in; (void)out_size; (void)ws_size;
    const float* x  = (const float*)d_in[0];
    const float* Wq = (const float*)d_in[1];
    const float* Wk = (const float*)d_in[2];
    const float* Wv = (const float*)d_in[3];
    const float* Wo = (const float*)d_in[4];

    u16* ws  = (u16*)d_ws;
    u16* xb  = ws;
    u16* wqb = ws + (size_t)1 * NTENS;
    u16* wkb = ws + (size_t)2 * NTENS;
    u16* wvb = ws + (size_t)3 * NTENS;
    u16* wob = ws + (size_t)4 * NTENS;
    u16* qb  = ws + (size_t)5 * NTENS;
    u16* kb  = ws + (size_t)6 * NTENS;
    // slot 7 (vb) unused since V is written pre-transposed by the QKV GEMM
    u16* yb  = ws + (size_t)8 * NTENS;
    u16* vt  = ws + (size_t)9 * NTENS;         // [bh][d][t]
    float* ct = (float*)(ws + (size_t)10 * NTENS);
    float* st = ct + 65536;

    k_convert <<<dim3(4096, 1, 6), 256, 0, stream>>>(x, Wq, Wk, Wv, Wo, ws, ct, st);
    k_gemm_qkv<<<dim3(16, 32, 3), 256, 0, stream>>>(xb, wqb, wkb, wvb, qb, kb, vt, ct, st);
    k_flash   <<<dim3(512), 256, 0, stream>>>(qb, kb, vt, yb);
    k_gemm_out<<<dim3(16, 32, 1), 256, 0, stream>>>(yb, wob, (float*)d_out);
}